// Round 9
// baseline (270.845 us; speedup 1.0000x reference)
//
#include <hip/hip_runtime.h>

#define N_NODES 100000
#define N_EDGES 1200000
#define N_GRAPHS 256
#define IN_C 5
#define HID_C 64
#define OUT_C 2

#define BSH 7
#define BNODES 128
#define NB ((N_NODES + BNODES - 1) / BNODES)        // 782
#define EPB 2048                                    // edges per block (binning) — 586 blocks
#define NBLK_E ((N_EDGES + EPB - 1) / EPB)
#define POOL_NPW 16

typedef unsigned int uint32;

// fp32 -> bf16 round-to-nearest-even (returns 16-bit pattern)
__device__ __forceinline__ uint32 f2bf(float f) {
    uint32 x = __float_as_uint(f);
    return (x + 0x7FFFu + ((x >> 16) & 1u)) >> 16;
}
__device__ __forceinline__ float bflo(uint32 r) { return __uint_as_float(r << 16); }
__device__ __forceinline__ float bfhi(uint32 r) { return __uint_as_float(r & 0xFFFF0000u); }

// ---- pass A: per-block LDS histogram of dst-buckets -> global bucket counts
__global__ void k_bcount(const int* __restrict__ dst, int* __restrict__ bcnt) {
    __shared__ int h[NB];
    for (int i = threadIdx.x; i < NB; i += blockDim.x) h[i] = 0;
    __syncthreads();
    int e0 = blockIdx.x * EPB;
    int e1 = e0 + EPB; if (e1 > N_EDGES) e1 = N_EDGES;
    for (int e = e0 + threadIdx.x; e < e1; e += blockDim.x)
        atomicAdd(&h[dst[e] >> BSH], 1);
    __syncthreads();
    for (int i = threadIdx.x; i < NB; i += blockDim.x)
        if (h[i]) atomicAdd(&bcnt[i], h[i]);
}

// ---- exclusive scan of bucket counts; bcur = cursor copy
__global__ void k_bscan(const int* __restrict__ bcnt, int* __restrict__ bstart,
                        int* __restrict__ bcur) {
    __shared__ int tmp[1024];
    int t = threadIdx.x;
    int v = (t < NB) ? bcnt[t] : 0;
    tmp[t] = v;
    __syncthreads();
    for (int off = 1; off < 1024; off <<= 1) {
        int a = (t >= off) ? tmp[t - off] : 0;
        __syncthreads();
        tmp[t] += a;
        __syncthreads();
    }
    if (t < NB) { int s = tmp[t] - v; bstart[t] = s; bcur[t] = s; }
}

// ---- pass B: bin edges into bucket regions, packed (dst_local<<17)|src
__global__ void k_bscatter(const int* __restrict__ src, const int* __restrict__ dst,
                           int* __restrict__ bcur, int* __restrict__ pairs) {
    __shared__ int h[NB];
    for (int i = threadIdx.x; i < NB; i += blockDim.x) h[i] = 0;
    __syncthreads();
    int e0 = blockIdx.x * EPB;
    int e1 = e0 + EPB; if (e1 > N_EDGES) e1 = N_EDGES;
    for (int e = e0 + threadIdx.x; e < e1; e += blockDim.x)
        atomicAdd(&h[dst[e] >> BSH], 1);
    __syncthreads();
    for (int i = threadIdx.x; i < NB; i += blockDim.x)
        if (h[i]) h[i] = atomicAdd(&bcur[i], h[i]);
    __syncthreads();
    for (int e = e0 + threadIdx.x; e < e1; e += blockDim.x) {
        int d = dst[e];
        int pos = atomicAdd(&h[d >> BSH], 1);
        pairs[pos] = ((d & (BNODES - 1)) << 17) | src[e];
    }
}

// ---- per-bucket counting sort -> dst-sorted CSR + row_start/cnt/dinv
__global__ void k_bsort(const int* __restrict__ pairs, const int* __restrict__ bstart,
                        const int* __restrict__ bcnt, int* __restrict__ csr,
                        int* __restrict__ rs, int* __restrict__ cnt,
                        float* __restrict__ dinv) {
    __shared__ int hist[BNODES];
    __shared__ int tmp[BNODES];
    __shared__ int cur[BNODES];
    int b = blockIdx.x;
    int t = threadIdx.x;
    if (t < BNODES) hist[t] = 0;
    __syncthreads();
    int s = bstart[b], n = bcnt[b];
    for (int i = t; i < n; i += blockDim.x)
        atomicAdd(&hist[pairs[s + i] >> 17], 1);
    __syncthreads();
    int v = (t < BNODES) ? hist[t] : 0;
    if (t < BNODES) tmp[t] = v;
    __syncthreads();
    for (int off = 1; off < BNODES; off <<= 1) {
        int a = (t < BNODES && t >= off) ? tmp[t - off] : 0;
        __syncthreads();
        if (t < BNODES) tmp[t] += a;
        __syncthreads();
    }
    if (t < BNODES) cur[t] = tmp[t] - v;
    __syncthreads();
    int base = b << BSH;
    if (t < BNODES && base + t < N_NODES) {
        rs[base + t] = s + tmp[t] - v;
        cnt[base + t] = v;
        dinv[base + t] = rsqrtf((float)v + 1.0f);
    }
    for (int i = t; i < n; i += blockDim.x) {
        int p = pairs[s + i];
        int pos = atomicAdd(&cur[p >> 17], 1);
        csr[s + pos] = p & 0x1FFFF;
    }
}

// ---- g1: packed bf16x2 table; thread = (node, channel-pair); float2 sW reads
__global__ void k_g1(const float* __restrict__ x, const float* __restrict__ W,
                     const float* __restrict__ dinv, uint32* __restrict__ g) {
    __shared__ float sW[IN_C * HID_C];
    int tid = threadIdx.x;
    for (int i = tid; i < IN_C * HID_C; i += blockDim.x) sW[i] = W[i];
    __syncthreads();
    int idx = blockIdx.x * blockDim.x + tid;   // node*32 + c2
    int n = idx >> 5, c2 = idx & 31;
    if (n >= N_NODES) return;
    float s0 = 0.f, s1 = 0.f;
#pragma unroll
    for (int k = 0; k < IN_C; ++k) {
        float xv = x[n * IN_C + k];
        float2 wv = *(const float2*)&sW[k * HID_C + 2 * c2];   // ds_read_b64, no conflict
        s0 += xv * wv.x;
        s1 += xv * wv.y;
    }
    float dv = dinv[n];
    g[idx] = (f2bf(s1 * dv) << 16) | f2bf(s0 * dv);
}

// ---- g2: packed bf16x2; k-outer register-blocked (4 nodes x 2ch per thread)
__global__ void k_g2(const float* __restrict__ h, const float* __restrict__ W,
                     const float* __restrict__ dinv, uint32* __restrict__ g) {
    __shared__ float sW[HID_C * HID_C];   // 16 KB
    __shared__ float sh[32][HID_C];       // 8 KB
    int tid = threadIdx.x;
    for (int i = tid; i < HID_C * HID_C; i += 256) sW[i] = W[i];
    int n0 = blockIdx.x * 32;
    for (int i = tid; i < 32 * HID_C; i += 256) ((float*)sh)[i] = h[(long)n0 * HID_C + i];
    __syncthreads();
    int ls = tid >> 5, c2 = tid & 31;     // ls in [0,8), c2 in [0,32)
    float2 acc0 = {0.f, 0.f}, acc1 = {0.f, 0.f}, acc2 = {0.f, 0.f}, acc3 = {0.f, 0.f};
    for (int k = 0; k < HID_C; k += 4) {
        float2 w0 = *(const float2*)&sW[(k + 0) * HID_C + 2 * c2];
        float2 w1 = *(const float2*)&sW[(k + 1) * HID_C + 2 * c2];
        float2 w2 = *(const float2*)&sW[(k + 2) * HID_C + 2 * c2];
        float2 w3 = *(const float2*)&sW[(k + 3) * HID_C + 2 * c2];
        float4 h0 = *(const float4*)&sh[0 * 8 + ls][k];
        float4 h1 = *(const float4*)&sh[1 * 8 + ls][k];
        float4 h2 = *(const float4*)&sh[2 * 8 + ls][k];
        float4 h3 = *(const float4*)&sh[3 * 8 + ls][k];
        acc0.x += h0.x * w0.x + h0.y * w1.x + h0.z * w2.x + h0.w * w3.x;
        acc0.y += h0.x * w0.y + h0.y * w1.y + h0.z * w2.y + h0.w * w3.y;
        acc1.x += h1.x * w0.x + h1.y * w1.x + h1.z * w2.x + h1.w * w3.x;
        acc1.y += h1.x * w0.y + h1.y * w1.y + h1.z * w2.y + h1.w * w3.y;
        acc2.x += h2.x * w0.x + h2.y * w1.x + h2.z * w2.x + h2.w * w3.x;
        acc2.y += h2.x * w0.y + h2.y * w1.y + h2.z * w2.y + h2.w * w3.y;
        acc3.x += h3.x * w0.x + h3.y * w1.x + h3.z * w2.x + h3.w * w3.x;
        acc3.y += h3.x * w0.y + h3.y * w1.y + h3.z * w2.y + h3.w * w3.y;
    }
#pragma unroll
    for (int j = 0; j < 4; ++j) {
        float2 a = (j == 0) ? acc0 : (j == 1) ? acc1 : (j == 2) ? acc2 : acc3;
        int ln = j * 8 + ls;
        float dv = dinv[n0 + ln];
        g[(long)(n0 + ln) * 32 + c2] = (f2bf(a.y * dv) << 16) | f2bf(a.x * dv);
    }
}

// ---- gather: one wave per node; lane=(half,c2); one wave-load covers 2 edge rows
__global__ void k_gather(const uint32* __restrict__ g, const int* __restrict__ csr,
                         const int* __restrict__ rs, const int* __restrict__ cnt,
                         const float* __restrict__ dinv, const float* __restrict__ b,
                         float* __restrict__ hout) {
    int v = __builtin_amdgcn_readfirstlane(
        blockIdx.x * (blockDim.x >> 6) + (threadIdx.x >> 6));
    if (v >= N_NODES) return;
    int lane = threadIdx.x & 63;
    int half = lane >> 5;     // edge parity
    int c2 = lane & 31;       // channel pair
    int k0 = rs[v];
    int n = cnt[v];
    float s0 = 0.f, s1 = 0.f;
    if (half == 0) {          // self-loop row, counted once
        uint32 r = g[(unsigned)v * 32 + c2];
        s0 = bflo(r); s1 = bfhi(r);
    }
    int i = 0;
    for (; i + 7 < n; i += 8) {   // 8 edges per iter, 4 wave-loads in flight
        int u0 = csr[k0 + i + 0], u1 = csr[k0 + i + 1];
        int u2 = csr[k0 + i + 2], u3 = csr[k0 + i + 3];
        int u4 = csr[k0 + i + 4], u5 = csr[k0 + i + 5];
        int u6 = csr[k0 + i + 6], u7 = csr[k0 + i + 7];
        int a0 = half ? u1 : u0;
        int a1 = half ? u3 : u2;
        int a2 = half ? u5 : u4;
        int a3 = half ? u7 : u6;
        uint32 r0 = g[(unsigned)a0 * 32 + c2];
        uint32 r1 = g[(unsigned)a1 * 32 + c2];
        uint32 r2 = g[(unsigned)a2 * 32 + c2];
        uint32 r3 = g[(unsigned)a3 * 32 + c2];
        s0 += (bflo(r0) + bflo(r1)) + (bflo(r2) + bflo(r3));
        s1 += (bfhi(r0) + bfhi(r1)) + (bfhi(r2) + bfhi(r3));
    }
    for (; i + 1 < n; i += 2) {
        int u0 = csr[k0 + i], u1 = csr[k0 + i + 1];
        int a = half ? u1 : u0;
        uint32 r = g[(unsigned)a * 32 + c2];
        s0 += bflo(r); s1 += bfhi(r);
    }
    if (i < n && half == 0) {     // odd leftover edge
        uint32 r = g[(unsigned)csr[k0 + i] * 32 + c2];
        s0 += bflo(r); s1 += bfhi(r);
    }
    s0 += __shfl_xor(s0, 32);
    s1 += __shfl_xor(s1, 32);
    if (half == 0) {
        float dv = dinv[v];
        float o0 = fmaxf(s0 * dv + b[2 * c2], 0.f);
        float o1 = fmaxf(s1 * dv + b[2 * c2 + 1], 0.f);
        *(float2*)(hout + (long)v * HID_C + 2 * c2) = make_float2(o0, o1);
    }
}

// ---- pool stage 1: wave scans POOL_NPW nodes, flush at graph boundaries
__global__ void k_pool1(const float* __restrict__ h, const int* __restrict__ batch,
                        float* __restrict__ pooled) {
    int wave = (blockIdx.x * blockDim.x + threadIdx.x) >> 6;
    int c = threadIdx.x & 63;
    int n0 = wave * POOL_NPW;
    if (n0 >= N_NODES) return;
    int n1 = n0 + POOL_NPW;
    if (n1 > N_NODES) n1 = N_NODES;
    int curg = batch[n0];
    float s = 0.f;
    for (int n = n0; n < n1; ++n) {
        int gg = batch[n];
        if (gg != curg) {
            atomicAdd(&pooled[curg * HID_C + c], s);
            s = 0.f;
            curg = gg;
        }
        s += h[(long)n * HID_C + c];
    }
    atomicAdd(&pooled[curg * HID_C + c], s);
}

// ---- mean + FC; one block (64 thr) per graph
__global__ void k_fc(const float* __restrict__ pooled, const int* __restrict__ batch,
                     const float* __restrict__ Wfc, const float* __restrict__ bfc,
                     float* __restrict__ out) {
    int g = blockIdx.x;
    int c = threadIdx.x;
    int lo = 0, hi = N_NODES;
    while (lo < hi) { int mid = (lo + hi) >> 1; if (batch[mid] < g) lo = mid + 1; else hi = mid; }
    int start = lo;
    hi = N_NODES;
    while (lo < hi) { int mid = (lo + hi) >> 1; if (batch[mid] < g + 1) lo = mid + 1; else hi = mid; }
    int n = lo - start;
    float pv = pooled[g * HID_C + c] / (float)(n > 0 ? n : 1);
    float o0 = pv * Wfc[c * OUT_C + 0];
    float o1 = pv * Wfc[c * OUT_C + 1];
#pragma unroll
    for (int off = 32; off > 0; off >>= 1) {
        o0 += __shfl_down(o0, off);
        o1 += __shfl_down(o1, off);
    }
    if (c == 0) {
        out[g * OUT_C + 0] = o0 + bfc[0];
        out[g * OUT_C + 1] = o1 + bfc[1];
    }
}

extern "C" void kernel_launch(void* const* d_in, const int* in_sizes, int n_in,
                              void* d_out, int out_size, void* d_ws, size_t ws_size,
                              hipStream_t stream) {
    const float* x    = (const float*)d_in[0];
    const int*   ei   = (const int*)d_in[1];
    const int*   src  = ei;
    const int*   dst  = ei + N_EDGES;
    const int*   batch= (const int*)d_in[2];
    const float* W1   = (const float*)d_in[3];
    const float* b1   = (const float*)d_in[4];
    const float* W2   = (const float*)d_in[5];
    const float* b2   = (const float*)d_in[6];
    const float* Wfc  = (const float*)d_in[7];
    const float* bfc  = (const float*)d_in[8];
    float* out = (float*)d_out;

    // workspace layout (4B elems)
    float*  ws     = (float*)d_ws;
    float*  dinv   = ws;                          // 100352
    int*    cnt    = (int*)(ws + 100352);         // 100352
    int*    rs     = cnt + 100352;                // 100352
    int*    bcnt   = rs + 100352;                 // 1024
    int*    bstart = bcnt + 1024;                 // 1024
    int*    bcur   = bstart + 1024;               // 1024
    int*    pairs  = bcur + 1024;                 // 1200128
    int*    csr    = pairs + 1200128;             // 1200128
    uint32* gtab   = (uint32*)(csr + 1200128);    // N*32 uint32 (bf16x2) = 12.8 MB
    float*  buf1   = (float*)(gtab + N_NODES * 32);   // N*64 fp32: h1 / h2
    float*  pooled = buf1 + N_NODES * HID_C;      // 256*64

    hipMemsetAsync(bcnt, 0, NB * sizeof(int), stream);
    hipMemsetAsync(pooled, 0, N_GRAPHS * HID_C * sizeof(float), stream);

    // ---- CSR build ----
    k_bcount<<<NBLK_E, 256, 0, stream>>>(dst, bcnt);
    k_bscan<<<1, 1024, 0, stream>>>(bcnt, bstart, bcur);
    k_bscatter<<<NBLK_E, 256, 0, stream>>>(src, dst, bcur, pairs);
    k_bsort<<<NB, 256, 0, stream>>>(pairs, bstart, bcnt, csr, rs, cnt, dinv);

    // ---- layer 1 ----
    k_g1<<<(N_NODES * 32) / 256, 256, 0, stream>>>(x, W1, dinv, gtab);
    k_gather<<<(N_NODES + 3) / 4, 256, 0, stream>>>(gtab, csr, rs, cnt, dinv, b1, buf1);

    // ---- layer 2 ----
    k_g2<<<N_NODES / 32, 256, 0, stream>>>(buf1, W2, dinv, gtab);
    k_gather<<<(N_NODES + 3) / 4, 256, 0, stream>>>(gtab, csr, rs, cnt, dinv, b2, buf1);

    // ---- pool + FC ----
    {
        int waves = (N_NODES + POOL_NPW - 1) / POOL_NPW;
        int blocks = (waves * 64 + 255) / 256;
        k_pool1<<<blocks, 256, 0, stream>>>(buf1, batch, pooled);
    }
    k_fc<<<N_GRAPHS, 64, 0, stream>>>(pooled, batch, Wfc, bfc, out);
}

// Round 10
// 244.279 us; speedup vs baseline: 1.1088x; 1.1088x over previous
//
#include <hip/hip_runtime.h>

#define N_NODES 100000
#define N_EDGES 1200000
#define N_GRAPHS 256
#define IN_C 5
#define HID_C 64
#define OUT_C 2

#define BSH 7
#define BNODES 128
#define NB ((N_NODES + BNODES - 1) / BNODES)        // 782
#define CAPB 2048                                   // fixed bucket capacity (E=1534, sigma=39)
#define EPB 2048                                    // edges per block (binning)
#define NBLK_E ((N_EDGES + EPB - 1) / EPB)          // 586
#define GNPW 8                                      // nodes per wave in fused gather2+pool

typedef unsigned int uint32;

// fp32 -> bf16 round-to-nearest-even (returns 16-bit pattern)
__device__ __forceinline__ uint32 f2bf(float f) {
    uint32 x = __float_as_uint(f);
    return (x + 0x7FFFu + ((x >> 16) & 1u)) >> 16;
}
__device__ __forceinline__ float bflo(uint32 r) { return __uint_as_float(r << 16); }
__device__ __forceinline__ float bfhi(uint32 r) { return __uint_as_float(r & 0xFFFF0000u); }

// ---- bin edges into fixed-capacity bucket regions, packed (dst_local<<17)|src
// bcnt (zeroed) doubles as reservation cursor and final bucket count.
__global__ void k_bscatter(const int* __restrict__ src, const int* __restrict__ dst,
                           int* __restrict__ bcnt, int* __restrict__ pairs) {
    __shared__ int h[NB];
    for (int i = threadIdx.x; i < NB; i += blockDim.x) h[i] = 0;
    __syncthreads();
    int e0 = blockIdx.x * EPB;
    int e1 = e0 + EPB; if (e1 > N_EDGES) e1 = N_EDGES;
    for (int e = e0 + threadIdx.x; e < e1; e += blockDim.x)
        atomicAdd(&h[dst[e] >> BSH], 1);
    __syncthreads();
    // reserve contiguous range per touched bucket; h[i] becomes local cursor
    for (int i = threadIdx.x; i < NB; i += blockDim.x)
        if (h[i]) h[i] = (i << 11) + atomicAdd(&bcnt[i], h[i]);
    __syncthreads();
    for (int e = e0 + threadIdx.x; e < e1; e += blockDim.x) {
        int d = dst[e];
        int pos = atomicAdd(&h[d >> BSH], 1);
        pairs[pos] = ((d & (BNODES - 1)) << 17) | src[e];
    }
}

// ---- per-bucket counting sort -> dst-sorted CSR (same fixed regions) + rs/cnt/dinv
__global__ void k_bsort(const int* __restrict__ pairs, const int* __restrict__ bcnt,
                        int* __restrict__ csr, int* __restrict__ rs,
                        int* __restrict__ cnt, float* __restrict__ dinv) {
    __shared__ int hist[BNODES];
    __shared__ int tmp[BNODES];
    __shared__ int cur[BNODES];
    int b = blockIdx.x;
    int t = threadIdx.x;
    if (t < BNODES) hist[t] = 0;
    __syncthreads();
    int s = b << 11;            // fixed bucket start
    int n = bcnt[b];
    for (int i = t; i < n; i += blockDim.x)
        atomicAdd(&hist[pairs[s + i] >> 17], 1);
    __syncthreads();
    int v = (t < BNODES) ? hist[t] : 0;
    if (t < BNODES) tmp[t] = v;
    __syncthreads();
    for (int off = 1; off < BNODES; off <<= 1) {
        int a = (t < BNODES && t >= off) ? tmp[t - off] : 0;
        __syncthreads();
        if (t < BNODES) tmp[t] += a;
        __syncthreads();
    }
    if (t < BNODES) cur[t] = tmp[t] - v;
    __syncthreads();
    int base = b << BSH;
    if (t < BNODES && base + t < N_NODES) {
        rs[base + t] = s + tmp[t] - v;
        cnt[base + t] = v;
        dinv[base + t] = rsqrtf((float)v + 1.0f);
    }
    for (int i = t; i < n; i += blockDim.x) {
        int p = pairs[s + i];
        int pos = atomicAdd(&cur[p >> 17], 1);
        csr[s + pos] = p & 0x1FFFF;
    }
}

// ---- g1: packed bf16x2 table; thread = (node, channel-pair); also zeroes pooled
__global__ void k_g1(const float* __restrict__ x, const float* __restrict__ W,
                     const float* __restrict__ dinv, uint32* __restrict__ g,
                     float* __restrict__ pooled) {
    __shared__ float sW[IN_C * HID_C];
    int tid = threadIdx.x;
    // first blocks also zero the pooled accumulator (read only by gather2p, later)
    int zi = blockIdx.x * blockDim.x + tid;
    if (zi < N_GRAPHS * HID_C) pooled[zi] = 0.f;
    for (int i = tid; i < IN_C * HID_C; i += blockDim.x) sW[i] = W[i];
    __syncthreads();
    int idx = blockIdx.x * blockDim.x + tid;   // node*32 + c2
    int n = idx >> 5, c2 = idx & 31;
    if (n >= N_NODES) return;
    float s0 = 0.f, s1 = 0.f;
#pragma unroll
    for (int k = 0; k < IN_C; ++k) {
        float xv = x[n * IN_C + k];
        float2 wv = *(const float2*)&sW[k * HID_C + 2 * c2];   // ds_read_b64
        s0 += xv * wv.x;
        s1 += xv * wv.y;
    }
    float dv = dinv[n];
    g[idx] = (f2bf(s1 * dv) << 16) | f2bf(s0 * dv);
}

// ---- g2: packed bf16x2; k-outer register-blocked (4 nodes x 2ch per thread)
__global__ void k_g2(const float* __restrict__ h, const float* __restrict__ W,
                     const float* __restrict__ dinv, uint32* __restrict__ g) {
    __shared__ float sW[HID_C * HID_C];   // 16 KB
    __shared__ float sh[32][HID_C];       // 8 KB
    int tid = threadIdx.x;
    for (int i = tid; i < HID_C * HID_C; i += 256) sW[i] = W[i];
    int n0 = blockIdx.x * 32;
    for (int i = tid; i < 32 * HID_C; i += 256) ((float*)sh)[i] = h[(long)n0 * HID_C + i];
    __syncthreads();
    int ls = tid >> 5, c2 = tid & 31;
    float2 acc0 = {0.f, 0.f}, acc1 = {0.f, 0.f}, acc2 = {0.f, 0.f}, acc3 = {0.f, 0.f};
    for (int k = 0; k < HID_C; k += 4) {
        float2 w0 = *(const float2*)&sW[(k + 0) * HID_C + 2 * c2];
        float2 w1 = *(const float2*)&sW[(k + 1) * HID_C + 2 * c2];
        float2 w2 = *(const float2*)&sW[(k + 2) * HID_C + 2 * c2];
        float2 w3 = *(const float2*)&sW[(k + 3) * HID_C + 2 * c2];
        float4 h0 = *(const float4*)&sh[0 * 8 + ls][k];
        float4 h1 = *(const float4*)&sh[1 * 8 + ls][k];
        float4 h2 = *(const float4*)&sh[2 * 8 + ls][k];
        float4 h3 = *(const float4*)&sh[3 * 8 + ls][k];
        acc0.x += h0.x * w0.x + h0.y * w1.x + h0.z * w2.x + h0.w * w3.x;
        acc0.y += h0.x * w0.y + h0.y * w1.y + h0.z * w2.y + h0.w * w3.y;
        acc1.x += h1.x * w0.x + h1.y * w1.x + h1.z * w2.x + h1.w * w3.x;
        acc1.y += h1.x * w0.y + h1.y * w1.y + h1.z * w2.y + h1.w * w3.y;
        acc2.x += h2.x * w0.x + h2.y * w1.x + h2.z * w2.x + h2.w * w3.x;
        acc2.y += h2.x * w0.y + h2.y * w1.y + h2.z * w2.y + h2.w * w3.y;
        acc3.x += h3.x * w0.x + h3.y * w1.x + h3.z * w2.x + h3.w * w3.x;
        acc3.y += h3.x * w0.y + h3.y * w1.y + h3.z * w2.y + h3.w * w3.y;
    }
#pragma unroll
    for (int j = 0; j < 4; ++j) {
        float2 a = (j == 0) ? acc0 : (j == 1) ? acc1 : (j == 2) ? acc2 : acc3;
        int ln = j * 8 + ls;
        float dv = dinv[n0 + ln];
        g[(long)(n0 + ln) * 32 + c2] = (f2bf(a.y * dv) << 16) | f2bf(a.x * dv);
    }
}

// ---- gather layer 1: one wave per node; lane=(half,c2); writes h1
__global__ void k_gather(const uint32* __restrict__ g, const int* __restrict__ csr,
                         const int* __restrict__ rs, const int* __restrict__ cnt,
                         const float* __restrict__ dinv, const float* __restrict__ b,
                         float* __restrict__ hout) {
    int v = __builtin_amdgcn_readfirstlane(
        blockIdx.x * (blockDim.x >> 6) + (threadIdx.x >> 6));
    if (v >= N_NODES) return;
    int lane = threadIdx.x & 63;
    int half = lane >> 5;
    int c2 = lane & 31;
    int k0 = rs[v];
    int n = cnt[v];
    float s0 = 0.f, s1 = 0.f;
    if (half == 0) {
        uint32 r = g[(unsigned)v * 32 + c2];
        s0 = bflo(r); s1 = bfhi(r);
    }
    int i = 0;
    for (; i + 7 < n; i += 8) {
        int u0 = csr[k0 + i + 0], u1 = csr[k0 + i + 1];
        int u2 = csr[k0 + i + 2], u3 = csr[k0 + i + 3];
        int u4 = csr[k0 + i + 4], u5 = csr[k0 + i + 5];
        int u6 = csr[k0 + i + 6], u7 = csr[k0 + i + 7];
        int a0 = half ? u1 : u0;
        int a1 = half ? u3 : u2;
        int a2 = half ? u5 : u4;
        int a3 = half ? u7 : u6;
        uint32 r0 = g[(unsigned)a0 * 32 + c2];
        uint32 r1 = g[(unsigned)a1 * 32 + c2];
        uint32 r2 = g[(unsigned)a2 * 32 + c2];
        uint32 r3 = g[(unsigned)a3 * 32 + c2];
        s0 += (bflo(r0) + bflo(r1)) + (bflo(r2) + bflo(r3));
        s1 += (bfhi(r0) + bfhi(r1)) + (bfhi(r2) + bfhi(r3));
    }
    for (; i + 1 < n; i += 2) {
        int u0 = csr[k0 + i], u1 = csr[k0 + i + 1];
        int a = half ? u1 : u0;
        uint32 r = g[(unsigned)a * 32 + c2];
        s0 += bflo(r); s1 += bfhi(r);
    }
    if (i < n && half == 0) {
        uint32 r = g[(unsigned)csr[k0 + i] * 32 + c2];
        s0 += bflo(r); s1 += bfhi(r);
    }
    s0 += __shfl_xor(s0, 32);
    s1 += __shfl_xor(s1, 32);
    if (half == 0) {
        float dv = dinv[v];
        float o0 = fmaxf(s0 * dv + b[2 * c2], 0.f);
        float o1 = fmaxf(s1 * dv + b[2 * c2 + 1], 0.f);
        *(float2*)(hout + (long)v * HID_C + 2 * c2) = make_float2(o0, o1);
    }
}

// ---- gather layer 2 fused with relu + mean-pool accumulate (no h2 write).
// One wave handles GNPW consecutive nodes; run-sum flushed at graph boundaries.
__global__ void k_gather2p(const uint32* __restrict__ g, const int* __restrict__ csr,
                           const int* __restrict__ rs, const int* __restrict__ cnt,
                           const float* __restrict__ dinv, const float* __restrict__ b,
                           const int* __restrict__ batch, float* __restrict__ pooled) {
    int wv = __builtin_amdgcn_readfirstlane(
        blockIdx.x * (blockDim.x >> 6) + (threadIdx.x >> 6));
    int n0 = wv * GNPW;
    if (n0 >= N_NODES) return;
    int n1 = n0 + GNPW; if (n1 > N_NODES) n1 = N_NODES;
    int lane = threadIdx.x & 63;
    int half = lane >> 5;
    int c2 = lane & 31;
    float bias0 = b[2 * c2], bias1 = b[2 * c2 + 1];
    float p0 = 0.f, p1 = 0.f;
    int curg = batch[n0];
    for (int v = n0; v < n1; ++v) {
        int k0 = rs[v];
        int n = cnt[v];
        float s0 = 0.f, s1 = 0.f;
        if (half == 0) {
            uint32 r = g[(unsigned)v * 32 + c2];
            s0 = bflo(r); s1 = bfhi(r);
        }
        int i = 0;
        for (; i + 7 < n; i += 8) {
            int u0 = csr[k0 + i + 0], u1 = csr[k0 + i + 1];
            int u2 = csr[k0 + i + 2], u3 = csr[k0 + i + 3];
            int u4 = csr[k0 + i + 4], u5 = csr[k0 + i + 5];
            int u6 = csr[k0 + i + 6], u7 = csr[k0 + i + 7];
            int a0 = half ? u1 : u0;
            int a1 = half ? u3 : u2;
            int a2 = half ? u5 : u4;
            int a3 = half ? u7 : u6;
            uint32 r0 = g[(unsigned)a0 * 32 + c2];
            uint32 r1 = g[(unsigned)a1 * 32 + c2];
            uint32 r2 = g[(unsigned)a2 * 32 + c2];
            uint32 r3 = g[(unsigned)a3 * 32 + c2];
            s0 += (bflo(r0) + bflo(r1)) + (bflo(r2) + bflo(r3));
            s1 += (bfhi(r0) + bfhi(r1)) + (bfhi(r2) + bfhi(r3));
        }
        for (; i + 1 < n; i += 2) {
            int u0 = csr[k0 + i], u1 = csr[k0 + i + 1];
            int a = half ? u1 : u0;
            uint32 r = g[(unsigned)a * 32 + c2];
            s0 += bflo(r); s1 += bfhi(r);
        }
        if (i < n && half == 0) {
            uint32 r = g[(unsigned)csr[k0 + i] * 32 + c2];
            s0 += bflo(r); s1 += bfhi(r);
        }
        s0 += __shfl_xor(s0, 32);
        s1 += __shfl_xor(s1, 32);
        float dv = dinv[v];
        float o0 = fmaxf(s0 * dv + bias0, 0.f);
        float o1 = fmaxf(s1 * dv + bias1, 0.f);
        int gg = batch[v];
        if (gg != curg) {
            if (half == 0) {
                atomicAdd(&pooled[curg * HID_C + 2 * c2], p0);
                atomicAdd(&pooled[curg * HID_C + 2 * c2 + 1], p1);
            }
            p0 = 0.f; p1 = 0.f; curg = gg;
        }
        p0 += o0; p1 += o1;
    }
    if (half == 0) {
        atomicAdd(&pooled[curg * HID_C + 2 * c2], p0);
        atomicAdd(&pooled[curg * HID_C + 2 * c2 + 1], p1);
    }
}

// ---- mean + FC; one block (64 thr) per graph
__global__ void k_fc(const float* __restrict__ pooled, const int* __restrict__ batch,
                     const float* __restrict__ Wfc, const float* __restrict__ bfc,
                     float* __restrict__ out) {
    int g = blockIdx.x;
    int c = threadIdx.x;
    int lo = 0, hi = N_NODES;
    while (lo < hi) { int mid = (lo + hi) >> 1; if (batch[mid] < g) lo = mid + 1; else hi = mid; }
    int start = lo;
    hi = N_NODES;
    while (lo < hi) { int mid = (lo + hi) >> 1; if (batch[mid] < g + 1) lo = mid + 1; else hi = mid; }
    int n = lo - start;
    float pv = pooled[g * HID_C + c] / (float)(n > 0 ? n : 1);
    float o0 = pv * Wfc[c * OUT_C + 0];
    float o1 = pv * Wfc[c * OUT_C + 1];
#pragma unroll
    for (int off = 32; off > 0; off >>= 1) {
        o0 += __shfl_down(o0, off);
        o1 += __shfl_down(o1, off);
    }
    if (c == 0) {
        out[g * OUT_C + 0] = o0 + bfc[0];
        out[g * OUT_C + 1] = o1 + bfc[1];
    }
}

extern "C" void kernel_launch(void* const* d_in, const int* in_sizes, int n_in,
                              void* d_out, int out_size, void* d_ws, size_t ws_size,
                              hipStream_t stream) {
    const float* x    = (const float*)d_in[0];
    const int*   ei   = (const int*)d_in[1];
    const int*   src  = ei;
    const int*   dst  = ei + N_EDGES;
    const int*   batch= (const int*)d_in[2];
    const float* W1   = (const float*)d_in[3];
    const float* b1   = (const float*)d_in[4];
    const float* W2   = (const float*)d_in[5];
    const float* b2   = (const float*)d_in[6];
    const float* Wfc  = (const float*)d_in[7];
    const float* bfc  = (const float*)d_in[8];
    float* out = (float*)d_out;

    // workspace layout (4B elems)
    float*  ws     = (float*)d_ws;
    float*  dinv   = ws;                          // 100352
    int*    cnt    = (int*)(ws + 100352);         // 100352
    int*    rs     = cnt + 100352;                // 100352
    int*    bcnt   = rs + 100352;                 // 1024
    int*    pairs  = bcnt + 1024;                 // NB*CAPB = 1601536
    int*    csr    = pairs + (NB * CAPB);         // 1601536
    uint32* gtab   = (uint32*)(csr + (NB * CAPB));// N*32 uint32 (bf16x2) = 12.8 MB
    float*  buf1   = (float*)(gtab + N_NODES * 32);   // N*64 fp32: h1
    float*  pooled = buf1 + N_NODES * HID_C;      // 256*64

    hipMemsetAsync(bcnt, 0, NB * sizeof(int), stream);

    // ---- CSR build (fixed-capacity buckets; no count/scan passes) ----
    k_bscatter<<<NBLK_E, 256, 0, stream>>>(src, dst, bcnt, pairs);
    k_bsort<<<NB, 256, 0, stream>>>(pairs, bcnt, csr, rs, cnt, dinv);

    // ---- layer 1 (k_g1 also zeroes pooled) ----
    k_g1<<<(N_NODES * 32) / 256, 256, 0, stream>>>(x, W1, dinv, gtab, pooled);
    k_gather<<<(N_NODES + 3) / 4, 256, 0, stream>>>(gtab, csr, rs, cnt, dinv, b1, buf1);

    // ---- layer 2 + fused pool ----
    k_g2<<<N_NODES / 32, 256, 0, stream>>>(buf1, W2, dinv, gtab);
    {
        int waves = (N_NODES + GNPW - 1) / GNPW;          // 12500
        int blocks = (waves + 3) / 4;                     // 3125
        k_gather2p<<<blocks, 256, 0, stream>>>(gtab, csr, rs, cnt, dinv, b2, batch, pooled);
    }

    // ---- FC ----
    k_fc<<<N_GRAPHS, 64, 0, stream>>>(pooled, batch, Wfc, bfc, out);
}

// Round 11
// 222.671 us; speedup vs baseline: 1.2163x; 1.0970x over previous
//
#include <hip/hip_runtime.h>

#define N_NODES 100000
#define N_EDGES 1200000
#define N_GRAPHS 256
#define IN_C 5
#define HID_C 64
#define OUT_C 2

#define BSH 7
#define BNODES 128
#define NB ((N_NODES + BNODES - 1) / BNODES)        // 782
#define CAPB 2048                                   // fixed bucket capacity (E=1534, sigma=39)
#define EPB 2048                                    // edges per block (binning)
#define NBLK_E ((N_EDGES + EPB - 1) / EPB)          // 586
#define GNPW 8                                      // nodes per wave in fused gather2+pool
#define G1NPW 4                                     // nodes per wave in fused gather1+g2

typedef unsigned int uint32;

// fp32 -> bf16 round-to-nearest-even (returns 16-bit pattern)
__device__ __forceinline__ uint32 f2bf(float f) {
    uint32 x = __float_as_uint(f);
    return (x + 0x7FFFu + ((x >> 16) & 1u)) >> 16;
}
__device__ __forceinline__ float bflo(uint32 r) { return __uint_as_float(r << 16); }
__device__ __forceinline__ float bfhi(uint32 r) { return __uint_as_float(r & 0xFFFF0000u); }

// ---- bin edges into fixed-capacity bucket regions, packed (dst_local<<17)|src
__global__ void k_bscatter(const int* __restrict__ src, const int* __restrict__ dst,
                           int* __restrict__ bcnt, int* __restrict__ pairs) {
    __shared__ int h[NB];
    for (int i = threadIdx.x; i < NB; i += blockDim.x) h[i] = 0;
    __syncthreads();
    int e0 = blockIdx.x * EPB;
    int e1 = e0 + EPB; if (e1 > N_EDGES) e1 = N_EDGES;
    for (int e = e0 + threadIdx.x; e < e1; e += blockDim.x)
        atomicAdd(&h[dst[e] >> BSH], 1);
    __syncthreads();
    for (int i = threadIdx.x; i < NB; i += blockDim.x)
        if (h[i]) h[i] = (i << 11) + atomicAdd(&bcnt[i], h[i]);
    __syncthreads();
    for (int e = e0 + threadIdx.x; e < e1; e += blockDim.x) {
        int d = dst[e];
        int pos = atomicAdd(&h[d >> BSH], 1);
        pairs[pos] = ((d & (BNODES - 1)) << 17) | src[e];
    }
}

// ---- per-bucket counting sort -> CSR + rs/cnt/dinv, FUSED with g1 epilogue:
// g1[node] = bf16x2((x[node] @ W1) * dinv[node]) for the block's 128 nodes.
__global__ void k_bsort_g1(const int* __restrict__ pairs, const int* __restrict__ bcnt,
                           const float* __restrict__ x, const float* __restrict__ W1,
                           int* __restrict__ csr, int* __restrict__ rs,
                           int* __restrict__ cnt, float* __restrict__ dinv,
                           uint32* __restrict__ g) {
    __shared__ int hist[BNODES];
    __shared__ int tmp[BNODES];
    __shared__ int cur[BNODES];
    __shared__ float sdv[BNODES];
    __shared__ __align__(16) float sW1[IN_C * HID_C];   // 1.25 KB
    __shared__ float sx[BNODES * IN_C];                 // 2.5 KB
    int b = blockIdx.x;
    int t = threadIdx.x;
    int base = b << BSH;
    if (t < BNODES) hist[t] = 0;
    for (int i = t; i < IN_C * HID_C; i += 256) sW1[i] = W1[i];
    for (int i = t; i < BNODES * IN_C; i += 256) {
        int gi = base * IN_C + i;
        sx[i] = (gi < N_NODES * IN_C) ? x[gi] : 0.f;
    }
    __syncthreads();
    int s = b << 11;            // fixed bucket start
    int n = bcnt[b];
    for (int i = t; i < n; i += 256)
        atomicAdd(&hist[pairs[s + i] >> 17], 1);
    __syncthreads();
    int v = (t < BNODES) ? hist[t] : 0;
    if (t < BNODES) tmp[t] = v;
    __syncthreads();
    for (int off = 1; off < BNODES; off <<= 1) {
        int a = (t < BNODES && t >= off) ? tmp[t - off] : 0;
        __syncthreads();
        if (t < BNODES) tmp[t] += a;
        __syncthreads();
    }
    float dv_t = rsqrtf((float)v + 1.0f);
    if (t < BNODES) {
        cur[t] = tmp[t] - v;
        sdv[t] = dv_t;
        if (base + t < N_NODES) {
            rs[base + t] = s + tmp[t] - v;
            cnt[base + t] = v;
            dinv[base + t] = dv_t;
        }
    }
    __syncthreads();
    for (int i = t; i < n; i += 256) {
        int p = pairs[s + i];
        int pos = atomicAdd(&cur[p >> 17], 1);
        csr[s + pos] = p & 0x1FFFF;
    }
    // ---- g1 epilogue: 128 nodes x 32 channel-pairs ----
    for (int idx = t; idx < BNODES * 32; idx += 256) {
        int nl = idx >> 5, c2 = idx & 31;
        int node = base + nl;
        if (node >= N_NODES) break;
        float s0 = 0.f, s1 = 0.f;
#pragma unroll
        for (int k = 0; k < IN_C; ++k) {
            float xv = sx[nl * IN_C + k];
            float2 wv = *(const float2*)&sW1[k * HID_C + 2 * c2];
            s0 += xv * wv.x;
            s1 += xv * wv.y;
        }
        float dv = sdv[nl];
        g[(unsigned)node * 32 + c2] = (f2bf(s1 * dv) << 16) | f2bf(s0 * dv);
    }
}

// ---- fused gather layer-1 + relu + g2 matmul: reads g1tab, writes g2tab.
// One wave handles G1NPW nodes; h1 row bounces through per-wave LDS, W2 in LDS.
__global__ void __launch_bounds__(256) k_gather_g2(
        const uint32* __restrict__ g1t, const int* __restrict__ csr,
        const int* __restrict__ rs, const int* __restrict__ cnt,
        const float* __restrict__ dinv, const float* __restrict__ b1,
        const float* __restrict__ W2, uint32* __restrict__ g2t) {
    __shared__ __align__(16) float sW2[HID_C * HID_C];  // 16 KB
    __shared__ float srow[4][HID_C];                    // 1 KB (per-wave row buffer)
    int tid = threadIdx.x;
    for (int i = tid; i < HID_C * HID_C; i += 256) sW2[i] = W2[i];
    __syncthreads();
    int w = tid >> 6;
    int wv = __builtin_amdgcn_readfirstlane(blockIdx.x * 4 + w);
    int n0 = wv * G1NPW;
    if (n0 >= N_NODES) return;
    int n1 = n0 + G1NPW; if (n1 > N_NODES) n1 = N_NODES;
    int lane = tid & 63;
    int half = lane >> 5;
    int c2 = lane & 31;
    float bias0 = b1[2 * c2], bias1 = b1[2 * c2 + 1];
    for (int v = n0; v < n1; ++v) {
        int k0 = rs[v];
        int n = cnt[v];
        float s0 = 0.f, s1 = 0.f;
        if (half == 0) {          // self-loop
            uint32 r = g1t[(unsigned)v * 32 + c2];
            s0 = bflo(r); s1 = bfhi(r);
        }
        int i = 0;
        for (; i + 7 < n; i += 8) {
            int u0 = csr[k0 + i + 0], u1 = csr[k0 + i + 1];
            int u2 = csr[k0 + i + 2], u3 = csr[k0 + i + 3];
            int u4 = csr[k0 + i + 4], u5 = csr[k0 + i + 5];
            int u6 = csr[k0 + i + 6], u7 = csr[k0 + i + 7];
            int a0 = half ? u1 : u0;
            int a1 = half ? u3 : u2;
            int a2 = half ? u5 : u4;
            int a3 = half ? u7 : u6;
            uint32 r0 = g1t[(unsigned)a0 * 32 + c2];
            uint32 r1 = g1t[(unsigned)a1 * 32 + c2];
            uint32 r2 = g1t[(unsigned)a2 * 32 + c2];
            uint32 r3 = g1t[(unsigned)a3 * 32 + c2];
            s0 += (bflo(r0) + bflo(r1)) + (bflo(r2) + bflo(r3));
            s1 += (bfhi(r0) + bfhi(r1)) + (bfhi(r2) + bfhi(r3));
        }
        for (; i + 1 < n; i += 2) {
            int u0 = csr[k0 + i], u1 = csr[k0 + i + 1];
            int a = half ? u1 : u0;
            uint32 r = g1t[(unsigned)a * 32 + c2];
            s0 += bflo(r); s1 += bfhi(r);
        }
        if (i < n && half == 0) {
            uint32 r = g1t[(unsigned)csr[k0 + i] * 32 + c2];
            s0 += bflo(r); s1 += bfhi(r);
        }
        s0 += __shfl_xor(s0, 32);
        s1 += __shfl_xor(s1, 32);
        float dv = dinv[v];
        float o0 = fmaxf(s0 * dv + bias0, 0.f);   // h1[v][2c2]
        float o1 = fmaxf(s1 * dv + bias1, 0.f);   // h1[v][2c2+1]
        // stage row in per-wave LDS (half 0 covers all 64 entries)
        if (half == 0) *(float2*)&srow[w][2 * c2] = make_float2(o0, o1);
        // g2 = (h1 @ W2) * dinv: halves split the k range, then combine
        int kb = half << 5;
        float a0 = 0.f, a1 = 0.f;
#pragma unroll 8
        for (int j = 0; j < 32; ++j) {
            float hv = srow[w][kb + j];
            float2 wvv = *(const float2*)&sW2[(kb + j) * HID_C + 2 * c2];
            a0 += hv * wvv.x;
            a1 += hv * wvv.y;
        }
        a0 += __shfl_xor(a0, 32);
        a1 += __shfl_xor(a1, 32);
        if (half == 0)
            g2t[(unsigned)v * 32 + c2] = (f2bf(a1 * dv) << 16) | f2bf(a0 * dv);
    }
}

// ---- gather layer 2 fused with relu + mean-pool accumulate
__global__ void k_gather2p(const uint32* __restrict__ g, const int* __restrict__ csr,
                           const int* __restrict__ rs, const int* __restrict__ cnt,
                           const float* __restrict__ dinv, const float* __restrict__ b,
                           const int* __restrict__ batch, float* __restrict__ pooled) {
    int wv = __builtin_amdgcn_readfirstlane(
        blockIdx.x * (blockDim.x >> 6) + (threadIdx.x >> 6));
    int n0 = wv * GNPW;
    if (n0 >= N_NODES) return;
    int n1 = n0 + GNPW; if (n1 > N_NODES) n1 = N_NODES;
    int lane = threadIdx.x & 63;
    int half = lane >> 5;
    int c2 = lane & 31;
    float bias0 = b[2 * c2], bias1 = b[2 * c2 + 1];
    float p0 = 0.f, p1 = 0.f;
    int curg = batch[n0];
    for (int v = n0; v < n1; ++v) {
        int k0 = rs[v];
        int n = cnt[v];
        float s0 = 0.f, s1 = 0.f;
        if (half == 0) {
            uint32 r = g[(unsigned)v * 32 + c2];
            s0 = bflo(r); s1 = bfhi(r);
        }
        int i = 0;
        for (; i + 7 < n; i += 8) {
            int u0 = csr[k0 + i + 0], u1 = csr[k0 + i + 1];
            int u2 = csr[k0 + i + 2], u3 = csr[k0 + i + 3];
            int u4 = csr[k0 + i + 4], u5 = csr[k0 + i + 5];
            int u6 = csr[k0 + i + 6], u7 = csr[k0 + i + 7];
            int a0 = half ? u1 : u0;
            int a1 = half ? u3 : u2;
            int a2 = half ? u5 : u4;
            int a3 = half ? u7 : u6;
            uint32 r0 = g[(unsigned)a0 * 32 + c2];
            uint32 r1 = g[(unsigned)a1 * 32 + c2];
            uint32 r2 = g[(unsigned)a2 * 32 + c2];
            uint32 r3 = g[(unsigned)a3 * 32 + c2];
            s0 += (bflo(r0) + bflo(r1)) + (bflo(r2) + bflo(r3));
            s1 += (bfhi(r0) + bfhi(r1)) + (bfhi(r2) + bfhi(r3));
        }
        for (; i + 1 < n; i += 2) {
            int u0 = csr[k0 + i], u1 = csr[k0 + i + 1];
            int a = half ? u1 : u0;
            uint32 r = g[(unsigned)a * 32 + c2];
            s0 += bflo(r); s1 += bfhi(r);
        }
        if (i < n && half == 0) {
            uint32 r = g[(unsigned)csr[k0 + i] * 32 + c2];
            s0 += bflo(r); s1 += bfhi(r);
        }
        s0 += __shfl_xor(s0, 32);
        s1 += __shfl_xor(s1, 32);
        float dv = dinv[v];
        float o0 = fmaxf(s0 * dv + bias0, 0.f);
        float o1 = fmaxf(s1 * dv + bias1, 0.f);
        int gg = batch[v];
        if (gg != curg) {
            if (half == 0) {
                atomicAdd(&pooled[curg * HID_C + 2 * c2], p0);
                atomicAdd(&pooled[curg * HID_C + 2 * c2 + 1], p1);
            }
            p0 = 0.f; p1 = 0.f; curg = gg;
        }
        p0 += o0; p1 += o1;
    }
    if (half == 0) {
        atomicAdd(&pooled[curg * HID_C + 2 * c2], p0);
        atomicAdd(&pooled[curg * HID_C + 2 * c2 + 1], p1);
    }
}

// ---- mean + FC; one block (64 thr) per graph
__global__ void k_fc(const float* __restrict__ pooled, const int* __restrict__ batch,
                     const float* __restrict__ Wfc, const float* __restrict__ bfc,
                     float* __restrict__ out) {
    int g = blockIdx.x;
    int c = threadIdx.x;
    int lo = 0, hi = N_NODES;
    while (lo < hi) { int mid = (lo + hi) >> 1; if (batch[mid] < g) lo = mid + 1; else hi = mid; }
    int start = lo;
    hi = N_NODES;
    while (lo < hi) { int mid = (lo + hi) >> 1; if (batch[mid] < g + 1) lo = mid + 1; else hi = mid; }
    int n = lo - start;
    float pv = pooled[g * HID_C + c] / (float)(n > 0 ? n : 1);
    float o0 = pv * Wfc[c * OUT_C + 0];
    float o1 = pv * Wfc[c * OUT_C + 1];
#pragma unroll
    for (int off = 32; off > 0; off >>= 1) {
        o0 += __shfl_down(o0, off);
        o1 += __shfl_down(o1, off);
    }
    if (c == 0) {
        out[g * OUT_C + 0] = o0 + bfc[0];
        out[g * OUT_C + 1] = o1 + bfc[1];
    }
}

extern "C" void kernel_launch(void* const* d_in, const int* in_sizes, int n_in,
                              void* d_out, int out_size, void* d_ws, size_t ws_size,
                              hipStream_t stream) {
    const float* x    = (const float*)d_in[0];
    const int*   ei   = (const int*)d_in[1];
    const int*   src  = ei;
    const int*   dst  = ei + N_EDGES;
    const int*   batch= (const int*)d_in[2];
    const float* W1   = (const float*)d_in[3];
    const float* b1   = (const float*)d_in[4];
    const float* W2   = (const float*)d_in[5];
    const float* b2   = (const float*)d_in[6];
    const float* Wfc  = (const float*)d_in[7];
    const float* bfc  = (const float*)d_in[8];
    float* out = (float*)d_out;

    // workspace layout (4B elems); bcnt+pooled adjacent for one memset
    float*  ws     = (float*)d_ws;
    int*    bcnt   = (int*)ws;                    // 1024
    float*  pooled = ws + 1024;                   // 16384
    float*  dinv   = pooled + 16384;              // 100352
    int*    cnt    = (int*)(dinv + 100352);       // 100352
    int*    rs     = cnt + 100352;                // 100352
    int*    pairs  = rs + 100352;                 // NB*CAPB = 1601536
    int*    csr    = pairs + (NB * CAPB);         // 1601536
    uint32* g1tab  = (uint32*)(csr + (NB * CAPB));// N*32 uint32 = 12.8 MB
    uint32* g2tab  = g1tab + N_NODES * 32;        // N*32 uint32 = 12.8 MB

    hipMemsetAsync(bcnt, 0, (1024 + 16384) * sizeof(float), stream);

    // ---- CSR build + g1 (fused) ----
    k_bscatter<<<NBLK_E, 256, 0, stream>>>(src, dst, bcnt, pairs);
    k_bsort_g1<<<NB, 256, 0, stream>>>(pairs, bcnt, x, W1, csr, rs, cnt, dinv, g1tab);

    // ---- layer-1 gather + relu + g2 matmul (fused; h1 never hits global) ----
    {
        int waves = (N_NODES + G1NPW - 1) / G1NPW;   // 25000
        int blocks = (waves + 3) / 4;                // 6250
        k_gather_g2<<<blocks, 256, 0, stream>>>(g1tab, csr, rs, cnt, dinv, b1, W2, g2tab);
    }

    // ---- layer-2 gather + relu + mean-pool (fused) ----
    {
        int waves = (N_NODES + GNPW - 1) / GNPW;     // 12500
        int blocks = (waves + 3) / 4;                // 3125
        k_gather2p<<<blocks, 256, 0, stream>>>(g2tab, csr, rs, cnt, dinv, b2, batch, pooled);
    }

    // ---- FC ----
    k_fc<<<N_GRAPHS, 64, 0, stream>>>(pooled, batch, Wfc, bfc, out);
}